// Round 7
// baseline (289.253 us; speedup 1.0000x reference)
//
#include <hip/hip_runtime.h>

#define D 64
#define K 400
#define KT 25            // K/16 code tiles
#define BLOCK 1024
#define WPB (BLOCK / 64) // 16 waves per block
#define LO_OFF 51200     // byte offset of lo-frags in workspace
#define NRM_OFF 102400   // byte offset of norms in workspace

typedef _Float16 f16x8 __attribute__((ext_vector_type(8)));
typedef float f32x4 __attribute__((ext_vector_type(4)));
typedef int i32x4 __attribute__((ext_vector_type(4)));

// scores = ||e||^2 - 2 x.e ; computed via f16 hi/lo split MFMA:
//   2e = eh + 2^-11 el,  x = xh + 2^-11 xl   (el, xl stored pre-scaled by 2^11)
//   dot(x,2e) ~= [xh.eh] + 2^-11 [xh.el + xl.eh]
// argmax over (dot - ||e||^2)  ==  argmin over score.
//
// R7: occupancy round. Best-so-far (R0: 66.7us) had B in LDS but 102KB ->
// 1 block/CU -> 4 waves/SIMD, latency-bound at MfmaUtil 24%. Here only the
// latency-critical HI fragments (51.2KB) + norms (1.6KB) live in LDS; the
// LO fragments (al-chain, latency-tolerant) are read from L2 (prepped in
// d_ws). LDS/block = 52.8KB -> 2 blocks/CU -> 8 waves/SIMD. a=2 keeps
// VGPR <= 64 (launch_bounds(1024,8)). Zero-alloca discipline from R5.

__global__ void vq_prep(const float* __restrict__ emb, void* __restrict__ ws) {
  _Float16* hi = (_Float16*)ws;                       // [25][2][64][8] f16
  _Float16* lo = (_Float16*)((char*)ws + LO_OFF);     // [25][2][64][8] f16
  float* nrm = (float*)((char*)ws + NRM_OFF);         // [400] f32
  int gid = blockIdx.x * blockDim.x + threadIdx.x;
  if (gid < KT * 2 * 64) {
    int t = gid >> 7;
    int c = (gid >> 6) & 1;
    int l = gid & 63;
    int code = t * 16 + (l & 15);
    int kb = ((l >> 4) << 3) + (c << 5);
    const float* ep = emb + code * D + kb;
    float4 u = *(const float4*)ep;
    float4 w = *(const float4*)(ep + 4);
    f16x8 h, g;
#define HL(j, val)                                     \
    do {                                               \
      float s_ = 2.0f * (val);                         \
      _Float16 t_ = (_Float16)s_;                      \
      h[j] = t_;                                       \
      g[j] = (_Float16)((s_ - (float)t_) * 2048.0f);   \
    } while (0)
    HL(0, u.x); HL(1, u.y); HL(2, u.z); HL(3, u.w);
    HL(4, w.x); HL(5, w.y); HL(6, w.z); HL(7, w.w);
#undef HL
    *(f16x8*)&hi[gid * 8] = h;
    *(f16x8*)&lo[gid * 8] = g;
  }
  if (gid < K) {
    const float4* ep = (const float4*)(emb + (size_t)gid * D);
    float4 s4 = {0.f, 0.f, 0.f, 0.f};
#pragma unroll
    for (int d = 0; d < 16; ++d) {
      float4 v = ep[d];
      s4.x = fmaf(v.x, v.x, s4.x);
      s4.y = fmaf(v.y, v.y, s4.y);
      s4.z = fmaf(v.z, v.z, s4.z);
      s4.w = fmaf(v.w, v.w, s4.w);
    }
    nrm[gid] = (s4.x + s4.y) + (s4.z + s4.w);
  }
}

#define SPL(hh, ll, j, val)                          \
  do {                                               \
    float v_ = (val);                                \
    _Float16 t_ = (_Float16)v_;                      \
    (hh)[j] = t_;                                    \
    (ll)[j] = (_Float16)((v_ - (float)t_) * 2048.0f);\
  } while (0)

__global__ __launch_bounds__(BLOCK, 8) void vq_mfma(
    const float* __restrict__ x,
    const float* __restrict__ emb,
    const void* __restrict__ ws,
    float* __restrict__ out,
    int nrows) {
  __shared__ __align__(16) _Float16 sHi[KT][2][64][8]; // 51,200 B
  __shared__ float sN[K];                              // 1,600 B

  const f16x8* gHi = (const f16x8*)ws;
  const f16x8* gLo = (const f16x8*)((const char*)ws + LO_OFF);
  const float* gN = (const float*)((const char*)ws + NRM_OFF);

  const int tid = threadIdx.x;

  // ---- stage hi-frags + norms into LDS (pure 16B copies, no convert) ----
  f16x8* sHiF = (f16x8*)&sHi[0][0][0][0];
  for (int e = tid; e < KT * 2 * 64; e += BLOCK) sHiF[e] = gHi[e];
  for (int k = tid; k < K; k += BLOCK) sN[k] = gN[k];
  __syncthreads();

  const int lane = tid & 63;
  const int wid = tid >> 6;
  const int gw = blockIdx.x * WPB + wid;
  const int nw = gridDim.x * WPB;
  const int l15 = lane & 15;
  const int q = lane >> 4;

// load + hi/lo-split one 16-row A tile into named frag vars
#define LOADX(a)                                                   \
  do {                                                             \
    const float* xp_ = x + (size_t)(row0 + (a)*16 + l15) * D + q * 8; \
    float4 u0_ = *(const float4*)xp_;                              \
    float4 u1_ = *(const float4*)(xp_ + 4);                        \
    float4 w0_ = *(const float4*)(xp_ + 32);                       \
    float4 w1_ = *(const float4*)(xp_ + 36);                       \
    SPL(xh##a##0, xl##a##0, 0, u0_.x);                             \
    SPL(xh##a##0, xl##a##0, 1, u0_.y);                             \
    SPL(xh##a##0, xl##a##0, 2, u0_.z);                             \
    SPL(xh##a##0, xl##a##0, 3, u0_.w);                             \
    SPL(xh##a##0, xl##a##0, 4, u1_.x);                             \
    SPL(xh##a##0, xl##a##0, 5, u1_.y);                             \
    SPL(xh##a##0, xl##a##0, 6, u1_.z);                             \
    SPL(xh##a##0, xl##a##0, 7, u1_.w);                             \
    SPL(xh##a##1, xl##a##1, 0, w0_.x);                             \
    SPL(xh##a##1, xl##a##1, 1, w0_.y);                             \
    SPL(xh##a##1, xl##a##1, 2, w0_.z);                             \
    SPL(xh##a##1, xl##a##1, 3, w0_.w);                             \
    SPL(xh##a##1, xl##a##1, 4, w1_.x);                             \
    SPL(xh##a##1, xl##a##1, 5, w1_.y);                             \
    SPL(xh##a##1, xl##a##1, 6, w1_.z);                             \
    SPL(xh##a##1, xl##a##1, 7, w1_.w);                             \
  } while (0)

// one 16x16 output tile: ah chain fed from LDS (low latency), al chain's
// lo-operands from L2 (latency hidden behind surrounding MFMAs)
#define PROCA(a)                                                               \
  do {                                                                         \
    f32x4 ah_ = {nn, nn, nn, nn};                                              \
    f32x4 al_ = {0.f, 0.f, 0.f, 0.f};                                          \
    ah_ = __builtin_amdgcn_mfma_f32_16x16x32_f16(xh##a##0, b0h, ah_, 0, 0, 0); \
    ah_ = __builtin_amdgcn_mfma_f32_16x16x32_f16(xh##a##1, b1h, ah_, 0, 0, 0); \
    al_ = __builtin_amdgcn_mfma_f32_16x16x32_f16(xl##a##0, b0h, al_, 0, 0, 0); \
    al_ = __builtin_amdgcn_mfma_f32_16x16x32_f16(xl##a##1, b1h, al_, 0, 0, 0); \
    al_ = __builtin_amdgcn_mfma_f32_16x16x32_f16(xh##a##0, b0l, al_, 0, 0, 0); \
    al_ = __builtin_amdgcn_mfma_f32_16x16x32_f16(xh##a##1, b1l, al_, 0, 0, 0); \
    _Pragma("unroll") for (int i_ = 0; i_ < 4; ++i_) {                         \
      float m_ = fmaf(al_[i_], 4.8828125e-4f, ah_[i_]); /* incl -||e||^2 */    \
      bool gt_ = m_ > bm##a[i_];                                               \
      bm##a[i_] = gt_ ? m_ : bm##a[i_];                                        \
      bt##a[i_] = gt_ ? t : bt##a[i_];                                         \
    }                                                                          \
  } while (0)

// one argmin-reduce step for tile-row group a at xor-mask mm
#define RSTA(a, mm)                                                        \
  _Pragma("unroll") for (int i_ = 0; i_ < 4; ++i_) {                       \
    float ov_ = __shfl_xor(bm##a[i_], (mm), 64);                           \
    int ok_ = __shfl_xor(bk##a[i_], (mm), 64);                             \
    bool tk_ = (ov_ > bm##a[i_]) || ((ov_ == bm##a[i_]) && (ok_ < bk##a[i_])); \
    bm##a[i_] = tk_ ? ov_ : bm##a[i_];                                     \
    bk##a[i_] = tk_ ? ok_ : bk##a[i_];                                     \
  }

// gather + coalesced write of the 16 rows of group a
#define WRA(a)                                                \
  do {                                                        \
    int j_ = (lane >> 2) & 3;                                 \
    int k01_ = (j_ & 1) ? bk##a[1] : bk##a[0];                \
    int k23_ = (j_ & 1) ? bk##a[3] : bk##a[2];                \
    int kk_ = (j_ & 2) ? k23_ : k01_;                         \
    int r_ = row0 + (a)*16 + (lane >> 2);                     \
    const f32x4* src_ = (const f32x4*)(emb + (size_t)kk_ * D);\
    f32x4* dst_ = (f32x4*)(out + (size_t)r_ * D);             \
    _Pragma("unroll") for (int s_ = 0; s_ < 4; ++s_) {        \
      int idx_ = (lane & 3) + (s_ << 2);                      \
      dst_[idx_] = src_[idx_];                                \
    }                                                         \
  } while (0)

  const int npair = nrows >> 5; // 32 rows per wave-iteration
  for (int g = gw; g < npair; g += nw) {
    const int row0 = g << 5;

    f16x8 xh00, xh01, xl00, xl01;
    f16x8 xh10, xh11, xl10, xl11;
    LOADX(0);
    LOADX(1);

    f32x4 bm0, bm1;
    i32x4 bt0, bt1;
    bm0 = bm1 = (f32x4){-3.4e38f, -3.4e38f, -3.4e38f, -3.4e38f};
    bt0 = bt1 = (i32x4){0, 0, 0, 0};

    // ---- 25 code tiles: 2 ds_read_b128 (hi) + 2 L2 loads (lo) -> 12 MFMAs ----
    for (int t = 0; t < KT; ++t) {
      f16x8 b0h = *(const f16x8*)&sHi[t][0][lane][0];
      f16x8 b1h = *(const f16x8*)&sHi[t][1][lane][0];
      f16x8 b0l = gLo[(t * 2 + 0) * 64 + lane];
      f16x8 b1l = gLo[(t * 2 + 1) * 64 + lane];
      float nn = -sN[t * 16 + l15];
      PROCA(0);
      PROCA(1);
    }

    // ---- argmin reduce across the 16 lanes of each row-group ----
    i32x4 bk0 = bt0 * 16 + l15;
    i32x4 bk1 = bt1 * 16 + l15;
#pragma unroll
    for (int mm = 1; mm <= 8; mm <<= 1) {
      RSTA(0, mm)
      RSTA(1, mm)
    }

    WRA(0);
    WRA(1);
  }
#undef LOADX
#undef PROCA
#undef RSTA
#undef WRA
}

extern "C" void kernel_launch(void* const* d_in, const int* in_sizes, int n_in,
                              void* d_out, int out_size, void* d_ws, size_t ws_size,
                              hipStream_t stream) {
  const float* x = (const float*)d_in[0];
  const float* emb = (const float*)d_in[1];
  float* out = (float*)d_out;
  int nrows = in_sizes[0] / D; // 262144
  vq_prep<<<13, 256, 0, stream>>>(emb, d_ws);
  vq_mfma<<<512, BLOCK, 0, stream>>>(x, emb, d_ws, out, nrows);
}

// Round 8
// 156.207 us; speedup vs baseline: 1.8517x; 1.8517x over previous
//
#include <hip/hip_runtime.h>

#define D 64
#define K 400
#define KT 25            // K/16 code tiles
#define BLOCK 256
#define WPB (BLOCK / 64) // 4 waves per block
#define NRM_OFF 102400   // byte offset of norms in workspace

typedef _Float16 f16x8 __attribute__((ext_vector_type(8)));
typedef float f32x4 __attribute__((ext_vector_type(4)));
typedef int i32x4 __attribute__((ext_vector_type(4)));

// scores = ||e||^2 - 2 x.e ; computed via f16 hi/lo split MFMA:
//   2e = eh + 2^-11 el,  x = xh + 2^-11 xl   (el, xl stored pre-scaled by 2^11)
//   dot(x,2e) ~= [xh.eh] + 2^-11 [xh.el + xl.eh]
// argmax over (dot - ||e||^2)  ==  argmin over score.
//
// R8: R6's no-LDS design (prep kernel writes fragment-ordered f16 codebook
// + norms to d_ws; main kernel reads B via coalesced L2-hot dwordx4) but
// with the occupancy ACTUALLY raised: R6 was grid-limited (4096 waves =
// 4/SIMD, same as R0). Here a=2 (32 rows/wave, ~56-70 VGPR working set)
// x 8192 waves (grid 2048) -> ~7-8 waves/SIMD resident, VGPR chosen
// freely by the compiler (R7 showed forcing it via launch_bounds spills
// catastrophically). No barriers, zero-alloca named-vector discipline.

__global__ void vq_prep(const float* __restrict__ emb, void* __restrict__ ws) {
  _Float16* B = (_Float16*)ws;                    // [25][4][64][8] f16
  float* nrm = (float*)((char*)ws + NRM_OFF);     // [400] f32
  int gid = blockIdx.x * blockDim.x + threadIdx.x;
  if (gid < KT * 4 * 64) {
    int t = gid >> 8;
    int f = (gid >> 6) & 3;
    int l = gid & 63;
    int code = t * 16 + (l & 15);
    int kb = ((l >> 4) << 3) + ((f >> 1) << 5);
    const float* ep = emb + code * D + kb;
    float4 u = *(const float4*)ep;
    float4 w = *(const float4*)(ep + 4);
    f16x8 h;
    if ((f & 1) == 0) {
      h[0] = (_Float16)(2.0f * u.x);
      h[1] = (_Float16)(2.0f * u.y);
      h[2] = (_Float16)(2.0f * u.z);
      h[3] = (_Float16)(2.0f * u.w);
      h[4] = (_Float16)(2.0f * w.x);
      h[5] = (_Float16)(2.0f * w.y);
      h[6] = (_Float16)(2.0f * w.z);
      h[7] = (_Float16)(2.0f * w.w);
    } else {
#define LOC(j, val)                                    \
      do {                                             \
        float s_ = 2.0f * (val);                       \
        _Float16 t_ = (_Float16)s_;                    \
        h[j] = (_Float16)((s_ - (float)t_) * 2048.0f); \
      } while (0)
      LOC(0, u.x); LOC(1, u.y); LOC(2, u.z); LOC(3, u.w);
      LOC(4, w.x); LOC(5, w.y); LOC(6, w.z); LOC(7, w.w);
#undef LOC
    }
    *(f16x8*)&B[gid * 8] = h;
  }
  if (gid < K) {
    const float4* ep = (const float4*)(emb + (size_t)gid * D);
    float4 s4 = {0.f, 0.f, 0.f, 0.f};
#pragma unroll
    for (int d = 0; d < 16; ++d) {
      float4 v = ep[d];
      s4.x = fmaf(v.x, v.x, s4.x);
      s4.y = fmaf(v.y, v.y, s4.y);
      s4.z = fmaf(v.z, v.z, s4.z);
      s4.w = fmaf(v.w, v.w, s4.w);
    }
    nrm[gid] = (s4.x + s4.y) + (s4.z + s4.w);
  }
}

#define SPL(hh, ll, j, val)                          \
  do {                                               \
    float v_ = (val);                                \
    _Float16 t_ = (_Float16)v_;                      \
    (hh)[j] = t_;                                    \
    (ll)[j] = (_Float16)((v_ - (float)t_) * 2048.0f);\
  } while (0)

__global__ __launch_bounds__(BLOCK) void vq_mfma(
    const float* __restrict__ x,
    const float* __restrict__ emb,
    const void* __restrict__ ws,
    float* __restrict__ out,
    int nrows) {
  const f16x8* B = (const f16x8*)ws;                       // [25*4*64]
  const float* nrm = (const float*)((const char*)ws + NRM_OFF);

  const int tid = threadIdx.x;
  const int lane = tid & 63;
  const int wid = tid >> 6;
  const int gw = blockIdx.x * WPB + wid;
  const int nw = gridDim.x * WPB;
  const int l15 = lane & 15;
  const int q = lane >> 4;

// load + hi/lo-split one 16-row A tile into named frag vars
#define LOADX(a)                                                   \
  do {                                                             \
    const float* xp_ = x + (size_t)(row0 + (a)*16 + l15) * D + q * 8; \
    float4 u0_ = *(const float4*)xp_;                              \
    float4 u1_ = *(const float4*)(xp_ + 4);                        \
    float4 w0_ = *(const float4*)(xp_ + 32);                       \
    float4 w1_ = *(const float4*)(xp_ + 36);                       \
    SPL(xh##a##0, xl##a##0, 0, u0_.x);                             \
    SPL(xh##a##0, xl##a##0, 1, u0_.y);                             \
    SPL(xh##a##0, xl##a##0, 2, u0_.z);                             \
    SPL(xh##a##0, xl##a##0, 3, u0_.w);                             \
    SPL(xh##a##0, xl##a##0, 4, u1_.x);                             \
    SPL(xh##a##0, xl##a##0, 5, u1_.y);                             \
    SPL(xh##a##0, xl##a##0, 6, u1_.z);                             \
    SPL(xh##a##0, xl##a##0, 7, u1_.w);                             \
    SPL(xh##a##1, xl##a##1, 0, w0_.x);                             \
    SPL(xh##a##1, xl##a##1, 1, w0_.y);                             \
    SPL(xh##a##1, xl##a##1, 2, w0_.z);                             \
    SPL(xh##a##1, xl##a##1, 3, w0_.w);                             \
    SPL(xh##a##1, xl##a##1, 4, w1_.x);                             \
    SPL(xh##a##1, xl##a##1, 5, w1_.y);                             \
    SPL(xh##a##1, xl##a##1, 6, w1_.z);                             \
    SPL(xh##a##1, xl##a##1, 7, w1_.w);                             \
  } while (0)

// one 16x16 output tile: 6 MFMAs + 4 selects, all state in named vectors
#define PROCA(a)                                                              \
  do {                                                                        \
    f32x4 ah_ = {nn, nn, nn, nn};                                             \
    f32x4 al_ = {0.f, 0.f, 0.f, 0.f};                                         \
    ah_ = __builtin_amdgcn_mfma_f32_16x16x32_f16(xh##a##0, b0, ah_, 0, 0, 0); \
    ah_ = __builtin_amdgcn_mfma_f32_16x16x32_f16(xh##a##1, b2, ah_, 0, 0, 0); \
    al_ = __builtin_amdgcn_mfma_f32_16x16x32_f16(xh##a##0, b1, al_, 0, 0, 0); \
    al_ = __builtin_amdgcn_mfma_f32_16x16x32_f16(xl##a##0, b0, al_, 0, 0, 0); \
    al_ = __builtin_amdgcn_mfma_f32_16x16x32_f16(xh##a##1, b3, al_, 0, 0, 0); \
    al_ = __builtin_amdgcn_mfma_f32_16x16x32_f16(xl##a##1, b2, al_, 0, 0, 0); \
    _Pragma("unroll") for (int i_ = 0; i_ < 4; ++i_) {                        \
      float m_ = fmaf(al_[i_], 4.8828125e-4f, ah_[i_]); /* incl -||e||^2 */   \
      bool gt_ = m_ > bm##a[i_];                                              \
      bm##a[i_] = gt_ ? m_ : bm##a[i_];                                       \
      bt##a[i_] = gt_ ? t : bt##a[i_];                                        \
    }                                                                         \
  } while (0)

// one argmin-reduce step for tile-row group a at xor-mask mm
#define RSTA(a, mm)                                                        \
  _Pragma("unroll") for (int i_ = 0; i_ < 4; ++i_) {                       \
    float ov_ = __shfl_xor(bm##a[i_], (mm), 64);                           \
    int ok_ = __shfl_xor(bk##a[i_], (mm), 64);                             \
    bool tk_ = (ov_ > bm##a[i_]) || ((ov_ == bm##a[i_]) && (ok_ < bk##a[i_])); \
    bm##a[i_] = tk_ ? ov_ : bm##a[i_];                                     \
    bk##a[i_] = tk_ ? ok_ : bk##a[i_];                                     \
  }

// gather + coalesced write of the 16 rows of group a
#define WRA(a)                                                \
  do {                                                        \
    int j_ = (lane >> 2) & 3;                                 \
    int k01_ = (j_ & 1) ? bk##a[1] : bk##a[0];                \
    int k23_ = (j_ & 1) ? bk##a[3] : bk##a[2];                \
    int kk_ = (j_ & 2) ? k23_ : k01_;                         \
    int r_ = row0 + (a)*16 + (lane >> 2);                     \
    const f32x4* src_ = (const f32x4*)(emb + (size_t)kk_ * D);\
    f32x4* dst_ = (f32x4*)(out + (size_t)r_ * D);             \
    _Pragma("unroll") for (int s_ = 0; s_ < 4; ++s_) {        \
      int idx_ = (lane & 3) + (s_ << 2);                      \
      dst_[idx_] = src_[idx_];                                \
    }                                                         \
  } while (0)

  const int npair = nrows >> 5; // 32 rows per wave-iteration
  for (int g = gw; g < npair; g += nw) {
    const int row0 = g << 5;

    f16x8 xh00, xh01, xl00, xl01;
    f16x8 xh10, xh11, xl10, xl11;
    LOADX(0);
    LOADX(1);

    f32x4 bm0, bm1;
    i32x4 bt0, bt1;
    bm0 = bm1 = (f32x4){-3.4e38f, -3.4e38f, -3.4e38f, -3.4e38f};
    bt0 = bt1 = (i32x4){0, 0, 0, 0};

    // ---- 25 code tiles: 4 coalesced L2-hot loads feed 12 MFMAs ----
    for (int t = 0; t < KT; ++t) {
      f16x8 b0 = B[(t * 4 + 0) * 64 + lane];
      f16x8 b1 = B[(t * 4 + 1) * 64 + lane];
      f16x8 b2 = B[(t * 4 + 2) * 64 + lane];
      f16x8 b3 = B[(t * 4 + 3) * 64 + lane];
      float nn = -nrm[t * 16 + l15];
      PROCA(0);
      PROCA(1);
    }

    // ---- argmin reduce across the 16 lanes of each row-group ----
    i32x4 bk0 = bt0 * 16 + l15;
    i32x4 bk1 = bt1 * 16 + l15;
#pragma unroll
    for (int mm = 1; mm <= 8; mm <<= 1) {
      RSTA(0, mm)
      RSTA(1, mm)
    }

    WRA(0);
    WRA(1);
  }
#undef LOADX
#undef PROCA
#undef RSTA
#undef WRA
}

extern "C" void kernel_launch(void* const* d_in, const int* in_sizes, int n_in,
                              void* d_out, int out_size, void* d_ws, size_t ws_size,
                              hipStream_t stream) {
  const float* x = (const float*)d_in[0];
  const float* emb = (const float*)d_in[1];
  float* out = (float*)d_out;
  int nrows = in_sizes[0] / D; // 262144
  vq_prep<<<25, 256, 0, stream>>>(emb, d_ws);
  vq_mfma<<<2048, BLOCK, 0, stream>>>(x, emb, d_ws, out, nrows);
}